// Round 10
// baseline (427.123 us; speedup 1.0000x reference)
//
#include <hip/hip_runtime.h>
#include <math.h>

// DIAGNOSTIC ROUND: identical half-row cooperative kernel, but BLOCKS=256
// (1/16 grid) so the qlayer dispatch exceeds ~160us and appears in the
// rocprof top-5 WITH counters. Purpose: read K' (kernel dur) + FETCH_SIZE
// directly from the table; then OH = dur_us - K', and production-kernel
// K = 377.5 - OH from Round 9. REVERT BLOCKS to 4096 next round.
//
// Kernel math unchanged: lane pair (2j,2j+1) owns row j; parity p = bit3.
// Wire0 gates via __shfl_xor(.,1); CNOTs = register permutations;
// normalization folded out (U orthogonal => T = ||x||^2).

#define BATCH   4194304
#define BLOCKS  256
#define TPB     256
#define PAIRS_PER_PASS (BLOCKS * (TPB / 2))

// cs[0..7] = cos(w/2), cs[8..15] = sin(w/2)   (w flat [2][4])
__global__ void prep_cs_kernel(const float* __restrict__ w, float* __restrict__ cs) {
    int i = threadIdx.x;
    if (i < 8) {
        float h = 0.5f * w[i];
        cs[i]     = cosf(h);
        cs[i + 8] = sinf(h);
    }
}

// in-register butterfly: (lo,hi) <- (c*lo - s*hi, s*lo + c*hi)
#define BFLY(lo, hi, c, s) do {                     \
        float _l = (lo), _h = (hi);                 \
        (lo) = fmaf(-(s), _h, (c) * _l);            \
        (hi) = fmaf( (s), _l, (c) * _h);            \
    } while (0)

__global__ __launch_bounds__(TPB) void qlayer_kernel(
        const float4* __restrict__ x4,
        const float*  __restrict__ cs,
        float2*       __restrict__ out2) {
    // Uniform (scalar) broadcast of the 16 trig constants.
    float C[8], S[8];
#pragma unroll
    for (int i = 0; i < 8; ++i) { C[i] = cs[i]; S[i] = cs[i + 8]; }

    const int gid = blockIdx.x * TPB + threadIdx.x;
    const int p   = gid & 1;                 // this lane's bit3 (wire0) value
    const float sgn = p ? 1.0f : -1.0f;      // cross-lane RY sign

    for (int r = (gid >> 1); r < BATCH; r += PAIRS_PER_PASS) {
        // lane's 8 amplitudes: states b = 8p + v, v = 0..7
        const float4 lo4 = x4[(size_t)r * 4 + 2 * p];
        const float4 hi4 = x4[(size_t)r * 4 + 2 * p + 1];
        float a0 = lo4.x, a1 = lo4.y, a2 = lo4.z, a3 = lo4.w;
        float a4 = hi4.x, a5 = hi4.y, a6 = hi4.z, a7 = hi4.w;

#pragma unroll
        for (int l = 0; l < 2; ++l) {
            const float c0 = C[4*l+0], s0 = S[4*l+0];
            const float c1 = C[4*l+1], s1 = S[4*l+1];
            const float c2 = C[4*l+2], s2 = S[4*l+2];
            const float c3 = C[4*l+3], s3 = S[4*l+3];

            // RY wire0 (bit3, cross-lane): a = c*a + sgn*s*partner
            {
                const float ss = sgn * s0;
                float b0 = __shfl_xor(a0, 1), b1 = __shfl_xor(a1, 1);
                float b2 = __shfl_xor(a2, 1), b3 = __shfl_xor(a3, 1);
                float b4 = __shfl_xor(a4, 1), b5 = __shfl_xor(a5, 1);
                float b6 = __shfl_xor(a6, 1), b7 = __shfl_xor(a7, 1);
                a0 = fmaf(ss, b0, c0 * a0); a1 = fmaf(ss, b1, c0 * a1);
                a2 = fmaf(ss, b2, c0 * a2); a3 = fmaf(ss, b3, c0 * a3);
                a4 = fmaf(ss, b4, c0 * a4); a5 = fmaf(ss, b5, c0 * a5);
                a6 = fmaf(ss, b6, c0 * a6); a7 = fmaf(ss, b7, c0 * a7);
            }
            // RY wire1 (bit2): pairs (v, v+4)
            BFLY(a0, a4, c1, s1); BFLY(a1, a5, c1, s1);
            BFLY(a2, a6, c1, s1); BFLY(a3, a7, c1, s1);
            // RY wire2 (bit1): (0,2),(1,3),(4,6),(5,7)
            BFLY(a0, a2, c2, s2); BFLY(a1, a3, c2, s2);
            BFLY(a4, a6, c2, s2); BFLY(a5, a7, c2, s2);
            // RY wire3 (bit0): (0,1),(2,3),(4,5),(6,7)
            BFLY(a0, a1, c3, s3); BFLY(a2, a3, c3, s3);
            BFLY(a4, a5, c3, s3); BFLY(a6, a7, c3, s3);

            // CNOT(0,1): control bit3 (=p), target bit2 -> p==1 lanes swap halves
            {
                float n0 = p ? a4 : a0, n4 = p ? a0 : a4;
                float n1 = p ? a5 : a1, n5 = p ? a1 : a5;
                float n2 = p ? a6 : a2, n6 = p ? a2 : a6;
                float n3 = p ? a7 : a3, n7 = p ? a3 : a7;
                a0 = n0; a1 = n1; a2 = n2; a3 = n3;
                a4 = n4; a5 = n5; a6 = n6; a7 = n7;
            }
            // CNOT(1,2): control bit2, target bit1 -> swap a4<->a6, a5<->a7 (free)
            { float t = a4; a4 = a6; a6 = t; t = a5; a5 = a7; a7 = t; }
            // CNOT(2,3): control bit1, target bit0 -> swap a2<->a3, a6<->a7 (free)
            { float t = a2; a2 = a3; a3 = t; t = a6; a6 = a7; a7 = t; }
            // CNOT(3,0): control bit0, target bit3 -> odd-v amps exchange lanes
            a1 = __shfl_xor(a1, 1); a3 = __shfl_xor(a3, 1);
            a5 = __shfl_xor(a5, 1); a7 = __shfl_xor(a7, 1);
        }

        // probabilities (unnormalized) and PauliZ expvals
        const float q0 = a0*a0, q1 = a1*a1, q2 = a2*a2, q3 = a3*a3;
        const float q4 = a4*a4, q5 = a5*a5, q6 = a6*a6, q7 = a7*a7;

        const float Tloc = ((q0+q1)+(q2+q3)) + ((q4+q5)+(q6+q7));
        const float PT   = __shfl_xor(Tloc, 1);
        const float T    = Tloc + PT;               // == ||x||^2 (U orthogonal)

        const float S0 = p ? Tloc : PT;             // bit3 set == hi lane's total
        float s1l = (q4+q5)+(q6+q7);                // bit2 set
        float s2l = (q2+q3)+(q6+q7);                // bit1 set
        float s3l = (q1+q3)+(q5+q7);                // bit0 set
        const float S1 = s1l + __shfl_xor(s1l, 1);
        const float S2 = s2l + __shfl_xor(s2l, 1);
        const float S3 = s3l + __shfl_xor(s3l, 1);

        const float invT = 1.0f / T;
        const float o0 = 1.0f - 2.0f * S0 * invT;
        const float o1 = 1.0f - 2.0f * S1 * invT;
        const float o2 = 1.0f - 2.0f * S2 * invT;
        const float o3 = 1.0f - 2.0f * S3 * invT;

        // pair writes the row's float4 as two unit-stride float2 stores
        out2[(size_t)2 * r + p] = p ? make_float2(o2, o3) : make_float2(o0, o1);
    }
}

extern "C" void kernel_launch(void* const* d_in, const int* in_sizes, int n_in,
                              void* d_out, int out_size, void* d_ws, size_t ws_size,
                              hipStream_t stream) {
    const float* x  = (const float*)d_in[0];   // [BATCH,16] f32
    const float* w  = (const float*)d_in[1];   // [2,4] f32
    float*       cs = (float*)d_ws;            // 16 floats scratch
    float2*      o2 = (float2*)d_out;          // [BATCH,4] f32 as float2 pairs

    prep_cs_kernel<<<1, 64, 0, stream>>>(w, cs);
    qlayer_kernel<<<BLOCKS, TPB, 0, stream>>>((const float4*)x, cs, o2);
}

// Round 11
// 376.010 us; speedup vs baseline: 1.1359x; 1.1359x over previous
//
#include <hip/hip_runtime.h>
#include <math.h>

// 4-qubit, 2-layer RY + CNOT-ring quantum layer, 4.19M rows.
// Half-row cooperative layout (lane pair owns a row; parity p = wire0 bit),
// now with 2 INDEPENDENT rows (A,B) per thread per iteration:
//  - 4 float4 loads in flight (was 2) to hide ~900cy HBM latency
//  - two independent gate chains interleavable by the scheduler to hide
//    the serial shfl (~120cy ds) hops in the circuit
//  - VGPR 12 -> ~24-32: breaks the compiler's minimal-register mov-bloat
// K accounting (R9/R10 diagnostics): OH ~= 266us, production K ~= dur - 266.

#define BATCH   4194304
#define BLOCKS  4096
#define TPB     256
#define PAIRS   (BLOCKS * (TPB / 2))   // 524288 pairs resident per iteration

// cs[0..7] = cos(w/2), cs[8..15] = sin(w/2)   (w flat [2][4])
__global__ void prep_cs_kernel(const float* __restrict__ w, float* __restrict__ cs) {
    int i = threadIdx.x;
    if (i < 8) {
        float h = 0.5f * w[i];
        cs[i]     = cosf(h);
        cs[i + 8] = sinf(h);
    }
}

// in-register butterfly: (lo,hi) <- (c*lo - s*hi, s*lo + c*hi)
#define BFLY(lo, hi, c, s) do {                     \
        float _l = (lo), _h = (hi);                 \
        (lo) = fmaf(-(s), _h, (c) * _l);            \
        (hi) = fmaf( (s), _l, (c) * _h);            \
    } while (0)

// Full circuit + expval epilogue for one row-half held in a0..a7.
// All control flow unrolled; all indices compile-time constant.
__device__ __forceinline__ float2 qrow(float a0, float a1, float a2, float a3,
                                       float a4, float a5, float a6, float a7,
                                       const float* __restrict__ C,
                                       const float* __restrict__ S,
                                       const int p, const float sgn) {
#pragma unroll
    for (int l = 0; l < 2; ++l) {
        const float c0 = C[4*l+0], s0 = S[4*l+0];
        const float c1 = C[4*l+1], s1 = S[4*l+1];
        const float c2 = C[4*l+2], s2 = S[4*l+2];
        const float c3 = C[4*l+3], s3 = S[4*l+3];

        // RY wire0 (bit3, cross-lane): a = c*a + sgn*s*partner
        {
            const float ss = sgn * s0;
            float b0 = __shfl_xor(a0, 1), b1 = __shfl_xor(a1, 1);
            float b2 = __shfl_xor(a2, 1), b3 = __shfl_xor(a3, 1);
            float b4 = __shfl_xor(a4, 1), b5 = __shfl_xor(a5, 1);
            float b6 = __shfl_xor(a6, 1), b7 = __shfl_xor(a7, 1);
            a0 = fmaf(ss, b0, c0 * a0); a1 = fmaf(ss, b1, c0 * a1);
            a2 = fmaf(ss, b2, c0 * a2); a3 = fmaf(ss, b3, c0 * a3);
            a4 = fmaf(ss, b4, c0 * a4); a5 = fmaf(ss, b5, c0 * a5);
            a6 = fmaf(ss, b6, c0 * a6); a7 = fmaf(ss, b7, c0 * a7);
        }
        // RY wire1 (bit2): pairs (v, v+4)
        BFLY(a0, a4, c1, s1); BFLY(a1, a5, c1, s1);
        BFLY(a2, a6, c1, s1); BFLY(a3, a7, c1, s1);
        // RY wire2 (bit1): (0,2),(1,3),(4,6),(5,7)
        BFLY(a0, a2, c2, s2); BFLY(a1, a3, c2, s2);
        BFLY(a4, a6, c2, s2); BFLY(a5, a7, c2, s2);
        // RY wire3 (bit0): (0,1),(2,3),(4,5),(6,7)
        BFLY(a0, a1, c3, s3); BFLY(a2, a3, c3, s3);
        BFLY(a4, a5, c3, s3); BFLY(a6, a7, c3, s3);

        // CNOT(0,1): control bit3 (=p), target bit2 -> p==1 lanes swap halves
        {
            float n0 = p ? a4 : a0, n4 = p ? a0 : a4;
            float n1 = p ? a5 : a1, n5 = p ? a1 : a5;
            float n2 = p ? a6 : a2, n6 = p ? a2 : a6;
            float n3 = p ? a7 : a3, n7 = p ? a3 : a7;
            a0 = n0; a1 = n1; a2 = n2; a3 = n3;
            a4 = n4; a5 = n5; a6 = n6; a7 = n7;
        }
        // CNOT(1,2): control bit2, target bit1 -> swap a4<->a6, a5<->a7 (rename)
        { float t = a4; a4 = a6; a6 = t; t = a5; a5 = a7; a7 = t; }
        // CNOT(2,3): control bit1, target bit0 -> swap a2<->a3, a6<->a7 (rename)
        { float t = a2; a2 = a3; a3 = t; t = a6; a6 = a7; a7 = t; }
        // CNOT(3,0): control bit0, target bit3 -> odd-v amps exchange lanes
        a1 = __shfl_xor(a1, 1); a3 = __shfl_xor(a3, 1);
        a5 = __shfl_xor(a5, 1); a7 = __shfl_xor(a7, 1);
    }

    // probabilities (unnormalized) and PauliZ expvals
    const float q0 = a0*a0, q1 = a1*a1, q2 = a2*a2, q3 = a3*a3;
    const float q4 = a4*a4, q5 = a5*a5, q6 = a6*a6, q7 = a7*a7;

    const float Tloc = ((q0+q1)+(q2+q3)) + ((q4+q5)+(q6+q7));
    const float PT   = __shfl_xor(Tloc, 1);
    const float T    = Tloc + PT;               // == ||x||^2 (U orthogonal)

    const float S0 = p ? Tloc : PT;             // bit3-set total
    float s1l = (q4+q5)+(q6+q7);                // bit2 set
    float s2l = (q2+q3)+(q6+q7);                // bit1 set
    float s3l = (q1+q3)+(q5+q7);                // bit0 set
    const float S1 = s1l + __shfl_xor(s1l, 1);
    const float S2 = s2l + __shfl_xor(s2l, 1);
    const float S3 = s3l + __shfl_xor(s3l, 1);

    const float invT = 1.0f / T;
    const float o0 = 1.0f - 2.0f * S0 * invT;
    const float o1 = 1.0f - 2.0f * S1 * invT;
    const float o2 = 1.0f - 2.0f * S2 * invT;
    const float o3 = 1.0f - 2.0f * S3 * invT;
    return p ? make_float2(o2, o3) : make_float2(o0, o1);
}

__global__ __launch_bounds__(TPB) void qlayer_kernel(
        const float4* __restrict__ x4,
        const float*  __restrict__ cs,
        float2*       __restrict__ out2) {
    float C[8], S[8];
#pragma unroll
    for (int i = 0; i < 8; ++i) { C[i] = cs[i]; S[i] = cs[i + 8]; }

    const int gid = blockIdx.x * TPB + threadIdx.x;
    const int p   = gid & 1;                 // this lane's bit3 (wire0) value
    const float sgn = p ? 1.0f : -1.0f;      // cross-lane RY sign
    const int j   = gid >> 1;                // pair index

#pragma unroll
    for (int i = 0; i < 2; ++i) {
        const size_t rA = (size_t)j + (size_t)(2 * i)     * PAIRS;
        const size_t rB = (size_t)j + (size_t)(2 * i + 1) * PAIRS;

        // issue all 4 loads up front (independent -> 4 in flight)
        const float4 A0 = x4[rA * 4 + 2 * p], A1 = x4[rA * 4 + 2 * p + 1];
        const float4 B0 = x4[rB * 4 + 2 * p], B1 = x4[rB * 4 + 2 * p + 1];

        const float2 oA = qrow(A0.x, A0.y, A0.z, A0.w, A1.x, A1.y, A1.z, A1.w,
                               C, S, p, sgn);
        const float2 oB = qrow(B0.x, B0.y, B0.z, B0.w, B1.x, B1.y, B1.z, B1.w,
                               C, S, p, sgn);

        out2[2 * rA + p] = oA;
        out2[2 * rB + p] = oB;
    }
#pragma unroll
    for (int i = 2; i < 4; ++i) {
        const size_t rA = (size_t)j + (size_t)(2 * i)     * PAIRS;
        const size_t rB = (size_t)j + (size_t)(2 * i + 1) * PAIRS;
        const float4 A0 = x4[rA * 4 + 2 * p], A1 = x4[rA * 4 + 2 * p + 1];
        const float4 B0 = x4[rB * 4 + 2 * p], B1 = x4[rB * 4 + 2 * p + 1];
        const float2 oA = qrow(A0.x, A0.y, A0.z, A0.w, A1.x, A1.y, A1.z, A1.w,
                               C, S, p, sgn);
        const float2 oB = qrow(B0.x, B0.y, B0.z, B0.w, B1.x, B1.y, B1.z, B1.w,
                               C, S, p, sgn);
        out2[2 * rA + p] = oA;
        out2[2 * rB + p] = oB;
    }
}

extern "C" void kernel_launch(void* const* d_in, const int* in_sizes, int n_in,
                              void* d_out, int out_size, void* d_ws, size_t ws_size,
                              hipStream_t stream) {
    const float* x  = (const float*)d_in[0];   // [BATCH,16] f32
    const float* w  = (const float*)d_in[1];   // [2,4] f32
    float*       cs = (float*)d_ws;            // 16 floats scratch
    float2*      o2 = (float2*)d_out;          // [BATCH,4] f32 as float2 pairs

    prep_cs_kernel<<<1, 64, 0, stream>>>(w, cs);
    qlayer_kernel<<<BLOCKS, TPB, 0, stream>>>((const float4*)x, cs, o2);
}